// Round 1
// baseline (334.812 us; speedup 1.0000x reference)
//
#include <hip/hip_runtime.h>
#include <math.h>

#define B_ 256
#define L_ 100
#define H_ 8
#define E_ 64
#define D_ 64

// Output offsets (floats), concatenated in reference return order:
// V[B,L,H,D], series[B,H,L,L], prior[B,H,L,L], sig[B,H,L,L], M[B,H,L]
#define OFF_SERIES ((size_t)B_ * L_ * H_ * D_)          // 13107200
#define OFF_PRIOR  (OFF_SERIES + (size_t)B_ * H_ * L_ * L_)
#define OFF_SIG    (OFF_PRIOR  + (size_t)B_ * H_ * L_ * L_)
#define OFF_M      (OFF_SIG    + (size_t)B_ * H_ * L_ * L_)

#define LOG2E 1.4426950408889634f
#define LN3   1.0986122886681098f
#define INV_SQRT_2PI 0.3989422804014327f

__device__ __forceinline__ float wave_reduce_max(float v) {
#pragma unroll
    for (int off = 32; off > 0; off >>= 1) v = fmaxf(v, __shfl_xor(v, off, 64));
    return v;
}
__device__ __forceinline__ float wave_reduce_sum(float v) {
#pragma unroll
    for (int off = 32; off > 0; off >>= 1) v += __shfl_xor(v, off, 64);
    return v;
}

// ---------------- Kernel A: prior + sig ----------------
// One block per (b,h). sigma[b,l,h] -> sig scalar per l (LDS), then
// elementwise over the 100x100 tile: coalesced writes of prior and sig.
__global__ __launch_bounds__(256) void prior_kernel(
    const float* __restrict__ sigma, const float* __restrict__ dist,
    float* __restrict__ prior, float* __restrict__ sigout) {
    const int bid = blockIdx.x;
    const int b = bid >> 3, h = bid & 7;
    __shared__ float sg[L_];
    const int t = threadIdx.x;
    if (t < L_) {
        float x = sigma[((size_t)b * L_ + t) * H_ + h];
        // sigmoid(5x) + 1e-5
        float s = 1.0f / (1.0f + exp2f(-5.0f * LOG2E * x)) + 1e-5f;
        // 3^s - 1, accurate for tiny results
        sg[t] = expm1f(s * LN3);
    }
    __syncthreads();
    const size_t base = (size_t)(b * H_ + h) * (L_ * L_);
    for (int idx = t; idx < L_ * L_; idx += 256) {
        int l = idx / L_;
        float sgm = sg[l];
        float d = dist[idx];
        float inv_s = 1.0f / sgm;
        float pr = INV_SQRT_2PI * inv_s *
                   exp2f(-0.5f * LOG2E * d * d * inv_s * inv_s);
        prior[base + idx]  = pr;
        sigout[base + idx] = sgm;
    }
}

// ---------------- Kernel B: scores -> series, M ----------------
// One block per (b,h), 4 waves, each wave owns 25 query rows.
// K staged to LDS transposed as float4 [e4][j] with XOR swizzle (j ^ (e4&7))
// -> conflict-free ds_read_b128 on both store and load. j padded to 128 with
// zero rows. Lane j holds score slots j and j+64.
__global__ __launch_bounds__(256) void scores_kernel(
    const float* __restrict__ Q, const float* __restrict__ K,
    float* __restrict__ series, float* __restrict__ Mout) {
    const int bid = blockIdx.x;
    const int b = bid >> 3, h = bid & 7;
    __shared__ float4 KT4[16 * 128];  // [e4][j^swz], 32 KB
    const int t = threadIdx.x;
    // stage K (zero-fill rows 100..127)
    for (int f = t; f < 16 * 128; f += 256) {
        int j = f >> 4, e4 = f & 15;
        float4 v = make_float4(0.f, 0.f, 0.f, 0.f);
        if (j < L_)
            v = *(const float4*)(K + (((size_t)b * L_ + j) * H_ + h) * E_ + e4 * 4);
        KT4[e4 * 128 + (j ^ (e4 & 7))] = v;
    }
    __syncthreads();

    const int wave = __builtin_amdgcn_readfirstlane(t >> 6);
    const int lane = t & 63;
    const int j2 = lane + 64;
    const bool valid1 = (j2 < L_);  // lane < 36

    for (int i = 0; i < 25; ++i) {
        const int l = wave * 25 + i;
        const float* qrow = Q + (((size_t)b * L_ + l) * H_ + h) * E_;
        float s0 = 0.f, s1 = 0.f;
#pragma unroll
        for (int e4 = 0; e4 < 16; ++e4) {
            float4 q  = *(const float4*)(qrow + e4 * 4);  // wave-uniform -> s_load
            float4 ka = KT4[e4 * 128 + (lane ^ (e4 & 7))];
            float4 kb = KT4[e4 * 128 + (j2 ^ (e4 & 7))];
            s0 += q.x * ka.x + q.y * ka.y + q.z * ka.z + q.w * ka.w;
            s1 += q.x * kb.x + q.y * kb.y + q.z * kb.z + q.w * kb.w;
        }
        // ---- row statistics over the 100 real j slots ----
        float m1   = valid1 ? fmaxf(s0, s1) : s0;
        float sum1 = valid1 ? (s0 + s1) : s0;
        int d0 = l - lane;  bool band0 = (d0 < 3) && (d0 > -3);
        int d1 = l - j2;    bool band1 = (d1 < 3) && (d1 > -3);
        float sp0 = band0 ? 0.f : s0;
        float sp1 = (valid1 && !band1) ? s1 : 0.f;
        float m2   = fmaxf(sp0, sp1);   // band zeros participate, like reference
        float sum2 = sp0 + sp1;
        m1   = wave_reduce_max(m1);
        m2   = wave_reduce_max(m2);
        sum1 = wave_reduce_sum(sum1);
        sum2 = wave_reduce_sum(sum2);
        // ---- softmax over attn = scale * scores (diag included in denom) ----
        const float c = 0.125f * LOG2E;
        float p0 = exp2f((s0 - m1) * c);
        float p1 = valid1 ? exp2f((s1 - m1) * c) : 0.f;
        float den = wave_reduce_sum(p0 + p1);
        float inv = 1.0f / den;
        float se0 = (lane == l) ? 0.f : p0 * inv;
        float se1 = (j2  == l) ? 0.f : p1 * inv;
        const size_t rowoff = ((size_t)(b * H_ + h) * L_ + l) * L_;
        series[rowoff + lane] = se0;
        if (valid1) series[rowoff + j2] = se1;
        if (lane == 0) {
            float M1 = m1 - sum1 * (1.0f / 100.0f);
            float M2 = m2 - sum2 * (1.0f / 94.0f);
            Mout[(size_t)(b * H_ + h) * L_ + l] = M1 - M2;
        }
    }
}

// ---------------- Kernel C: V = series @ values ----------------
// One block per (b,h). V staged in LDS [j][d] (lane=d reads conflict-free).
// series rows read back from global with wave-uniform addresses (s_load);
// 5 rows per pass amortize the LDS read.
__global__ __launch_bounds__(256) void pv_kernel(
    const float* __restrict__ Vin, const float* __restrict__ series,
    float* __restrict__ Vout) {
    const int bid = blockIdx.x;
    const int b = bid >> 3, h = bid & 7;
    __shared__ float Vl[L_ * D_];  // 25.6 KB
    const int t = threadIdx.x;
    for (int f = t; f < L_ * 16; f += 256) {
        int j = f >> 4, q = f & 15;
        *(float4*)(Vl + j * D_ + q * 4) =
            *(const float4*)(Vin + (((size_t)b * L_ + j) * H_ + h) * D_ + q * 4);
    }
    __syncthreads();

    const int wave = __builtin_amdgcn_readfirstlane(t >> 6);
    const int lane = t & 63;  // = d

    for (int i0 = 0; i0 < 25; i0 += 5) {
        const int l0 = wave * 25 + i0;
        const float* prow = series + ((size_t)(b * H_ + h) * L_ + l0) * L_;
        float acc0 = 0.f, acc1 = 0.f, acc2 = 0.f, acc3 = 0.f, acc4 = 0.f;
#pragma unroll 4
        for (int j = 0; j < L_; ++j) {
            float v = Vl[j * D_ + lane];
            acc0 += prow[0 * L_ + j] * v;   // wave-uniform -> s_load
            acc1 += prow[1 * L_ + j] * v;
            acc2 += prow[2 * L_ + j] * v;
            acc3 += prow[3 * L_ + j] * v;
            acc4 += prow[4 * L_ + j] * v;
        }
        Vout[(((size_t)b * L_ + (l0 + 0)) * H_ + h) * D_ + lane] = acc0;
        Vout[(((size_t)b * L_ + (l0 + 1)) * H_ + h) * D_ + lane] = acc1;
        Vout[(((size_t)b * L_ + (l0 + 2)) * H_ + h) * D_ + lane] = acc2;
        Vout[(((size_t)b * L_ + (l0 + 3)) * H_ + h) * D_ + lane] = acc3;
        Vout[(((size_t)b * L_ + (l0 + 4)) * H_ + h) * D_ + lane] = acc4;
    }
}

extern "C" void kernel_launch(void* const* d_in, const int* in_sizes, int n_in,
                              void* d_out, int out_size, void* d_ws, size_t ws_size,
                              hipStream_t stream) {
    const float* Q     = (const float*)d_in[0];
    const float* K     = (const float*)d_in[1];
    const float* V     = (const float*)d_in[2];
    const float* sigma = (const float*)d_in[3];
    const float* dist  = (const float*)d_in[4];
    // d_in[5] = attn_mask, unused (mask_flag=False)

    float* out    = (float*)d_out;
    float* Vout   = out;
    float* series = out + OFF_SERIES;
    float* prior  = out + OFF_PRIOR;
    float* sigout = out + OFF_SIG;
    float* Mout   = out + OFF_M;

    dim3 grid(B_ * H_), block(256);
    hipLaunchKernelGGL(prior_kernel,  grid, block, 0, stream, sigma, dist, prior, sigout);
    hipLaunchKernelGGL(scores_kernel, grid, block, 0, stream, Q, K, series, Mout);
    hipLaunchKernelGGL(pv_kernel,     grid, block, 0, stream, V, series, Vout);
}